// Round 1
// baseline (19935.515 us; speedup 1.0000x reference)
//
#include <hip/hip_runtime.h>
#include <cmath>

#define BATCH 256
#define TSTEPS 512
#define NDIM 256
#define HDIM 256
#define WASH 64
#define TOUT (TSTEPS - WASH)   /* 448 */
#define NB 4                   /* batch rows per block */
#define NBLK (BATCH / NB)      /* 64 blocks */
#define NTHREADS 512
#define KX (2 * NDIM + 2)      /* 514 */

__device__ __forceinline__ float sigf(float v) {
    return 1.0f / (1.0f + expf(-v));
}

extern "C" __global__ void __launch_bounds__(NTHREADS, 2)
causal_loop_kernel(const int* __restrict__ settings,   // [B][T][2] int32
                   const float* __restrict__ noiseA,   // [B][T][N]
                   const float* __restrict__ noiseB,   // [B][T][N]
                   const float* __restrict__ WinA,     // [2][N]
                   const float* __restrict__ WrecA,    // [N][N]
                   const float* __restrict__ WinB,     // [2][N]
                   const float* __restrict__ WrecB,    // [N][N]
                   const float* __restrict__ Wx,       // [514][768]
                   const float* __restrict__ bg,       // [768]
                   const float* __restrict__ Wout,     // [256][2]
                   const float* __restrict__ bout,     // [2]
                   float* __restrict__ out)
{
    __shared__ float sA[NB][NDIM];
    __shared__ float sB[NB][NDIM];
    __shared__ float x[NB][520];          // padded row (16B aligned)
    __shared__ float hz[NB][HDIM];        // sigmoid(z_pre)
    __shared__ float hn[NB][HDIM];        // tanh(n_pre)
    __shared__ float bitsf[NB][2];
    __shared__ float ring[2][NB][2];      // delay buffer (D=2)
    __shared__ float logits[NB][2];

    const int tid = threadIdx.x;
    const int b0  = blockIdx.x * NB;

    for (int i = tid; i < NB * NDIM; i += NTHREADS) {
        sA[i >> 8][i & 255] = 0.0f;
        sB[i >> 8][i & 255] = 0.0f;
    }
    if (tid < 16) ((float*)ring)[tid] = 0.0f;
    __syncthreads();

    // Static per-thread role: p=0 -> z-part of gx + reservoir A; p=1 -> n-part + reservoir B
    const int p = tid >> 8;
    const int c = tid & 255;
    const float* wcol = Wx + (p * 512 + c);   // used columns: [0,256) and [512,768)
    const float  bgc  = bg[p * 512 + c];
    const float* wrec = (p == 0) ? WrecA : WrecB;
    const float  win0 = (p == 0) ? WinA[c]        : WinB[c];
    const float  win1 = (p == 0) ? WinA[NDIM + c] : WinB[NDIM + c];

    float* out0 = out;
    float* out1 = out + (size_t)BATCH * TOUT;
    float* out2 = out + (size_t)2 * BATCH * TOUT;

    for (int t = 0; t < TSTEPS; ++t) {
        // ---- X: build x = [sA + nA, sB + nB, spins]; log bits
        for (int idx = tid; idx < NB * NDIM; idx += NTHREADS) {
            const int r = idx >> 8, cc = idx & 255;
            const size_t off = ((size_t)(b0 + r) * TSTEPS + t) * NDIM + cc;
            x[r][cc]        = sA[r][cc] + noiseA[off];
            x[r][NDIM + cc] = sB[r][cc] + noiseB[off];
        }
        if (tid < NB * 2) {
            const int r = tid >> 1, j = tid & 1;
            const float bit = (float)settings[((size_t)(b0 + r) * TSTEPS + t) * 2 + j];
            bitsf[r][j] = bit;
            x[r][2 * NDIM + j] = 2.0f * bit - 1.0f;
            if (t >= WASH)
                out2[((size_t)(b0 + r) * TOUT + (t - WASH)) * 2 + j] = bit;
        }
        __syncthreads();

        // ---- G: gx (z-part or n-part), 4 batch rows per thread, paired accumulators
        {
            float e0 = bgc, e1 = 0.0f, e2 = bgc, e3 = 0.0f;
            float e4 = bgc, e5 = 0.0f, e6 = bgc, e7 = 0.0f;
            const float* w = wcol;
            for (int k = 0; k < KX; k += 2, w += 2 * 768) {
                const float w0 = w[0], w1 = w[768];
                e0 = fmaf(x[0][k], w0, e0); e1 = fmaf(x[0][k + 1], w1, e1);
                e2 = fmaf(x[1][k], w0, e2); e3 = fmaf(x[1][k + 1], w1, e3);
                e4 = fmaf(x[2][k], w0, e4); e5 = fmaf(x[2][k + 1], w1, e5);
                e6 = fmaf(x[3][k], w0, e6); e7 = fmaf(x[3][k + 1], w1, e7);
            }
            const float a0 = e0 + e1, a1 = e2 + e3, a2 = e4 + e5, a3 = e6 + e7;
            if (p == 0) {
                hz[0][c] = sigf(a0); hz[1][c] = sigf(a1);
                hz[2][c] = sigf(a2); hz[3][c] = sigf(a3);
            } else {
                hn[0][c] = tanhf(a0); hn[1][c] = tanhf(a1);
                hn[2][c] = tanhf(a2); hn[3][c] = tanhf(a3);
            }
        }
        __syncthreads();

        // ---- L: logits[r][j] = sum_c (1-z)*n * Wout[c][j] + bout[j]  (one wave per (r,j))
        {
            const int wv = tid >> 6, lane = tid & 63;
            const int r = wv >> 1, j = wv & 1;
            float part = 0.0f;
            for (int cc = lane; cc < HDIM; cc += 64) {
                const float hval = (1.0f - hz[r][cc]) * hn[r][cc];
                part = fmaf(hval, Wout[cc * 2 + j], part);
            }
            #pragma unroll
            for (int s = 32; s > 0; s >>= 1) part += __shfl_down(part, s, 64);
            if (lane == 0) logits[r][j] = part + bout[j];
        }
        // ---- S: new state for side p, column c, 4 rows (uses ring = logits(t-2))
        float v0, v1, v2, v3;
        {
            const float* sloc = (p == 0) ? &sA[0][0] : &sB[0][0];
            const float d0 = ring[t & 1][0][p], d1 = ring[t & 1][1][p];
            const float d2 = ring[t & 1][2][p], d3 = ring[t & 1][3][p];
            float e0 = fmaf(bitsf[0][p], win0, d0 * win1), e1 = 0.0f;
            float e2 = fmaf(bitsf[1][p], win0, d1 * win1), e3 = 0.0f;
            float e4 = fmaf(bitsf[2][p], win0, d2 * win1), e5 = 0.0f;
            float e6 = fmaf(bitsf[3][p], win0, d3 * win1), e7 = 0.0f;
            const float* w = wrec + c;
            for (int k = 0; k < NDIM; k += 2, w += 2 * NDIM) {
                const float w0 = w[0], w1 = w[NDIM];
                e0 = fmaf(sloc[0 * NDIM + k], w0, e0); e1 = fmaf(sloc[0 * NDIM + k + 1], w1, e1);
                e2 = fmaf(sloc[1 * NDIM + k], w0, e2); e3 = fmaf(sloc[1 * NDIM + k + 1], w1, e3);
                e4 = fmaf(sloc[2 * NDIM + k], w0, e4); e5 = fmaf(sloc[2 * NDIM + k + 1], w1, e5);
                e6 = fmaf(sloc[3 * NDIM + k], w0, e6); e7 = fmaf(sloc[3 * NDIM + k + 1], w1, e7);
            }
            v0 = tanhf(e0 + e1); v1 = tanhf(e2 + e3);
            v2 = tanhf(e4 + e5); v3 = tanhf(e6 + e7);
        }
        __syncthreads();   // all reads of sA/sB/ring/hz/hn complete; logits ready

        // ---- W/O: commit states, ring, sign outputs
        {
            float* sloc = (p == 0) ? &sA[0][0] : &sB[0][0];
            sloc[0 * NDIM + c] = v0; sloc[1 * NDIM + c] = v1;
            sloc[2 * NDIM + c] = v2; sloc[3 * NDIM + c] = v3;
        }
        if (tid < NB * 2) {
            const int r = tid >> 1, j = tid & 1;
            const float lg = logits[r][j];
            ring[t & 1][r][j] = lg;
            if (t >= WASH) {
                const float sg = (lg > 0.0f) ? 1.0f : ((lg < 0.0f) ? -1.0f : 0.0f);
                (j == 0 ? out0 : out1)[(size_t)(b0 + r) * TOUT + (t - WASH)] = sg;
            }
        }
        __syncthreads();
    }
}

extern "C" void kernel_launch(void* const* d_in, const int* in_sizes, int n_in,
                              void* d_out, int out_size, void* d_ws, size_t ws_size,
                              hipStream_t stream) {
    (void)in_sizes; (void)n_in; (void)d_ws; (void)ws_size; (void)out_size;
    causal_loop_kernel<<<NBLK, NTHREADS, 0, stream>>>(
        (const int*)d_in[0],     // settings_seq
        (const float*)d_in[1],   // noise_seq_A
        (const float*)d_in[2],   // noise_seq_B
        (const float*)d_in[3],   // W_in_A
        (const float*)d_in[4],   // W_rec_A
        (const float*)d_in[5],   // W_in_B
        (const float*)d_in[6],   // W_rec_B
        (const float*)d_in[7],   // Wx  (d_in[8]=Wh unused since h0==0)
        (const float*)d_in[9],   // b_gru
        (const float*)d_in[10],  // Wout
        (const float*)d_in[11],  // b_out
        (float*)d_out);
}

// Round 2
// 7164.980 us; speedup vs baseline: 2.7824x; 2.7824x over previous
//
#include <hip/hip_runtime.h>
#include <cmath>

#define BATCH 256
#define TSTEPS 512
#define NDIM 256
#define WASH 64
#define TOUT (TSTEPS - WASH)   /* 448 */
#define NB 4                   /* batch rows per block */
#define NBLK (BATCH / NB)      /* 64 blocks */
#define NT 1024
#define KX 514

__device__ __forceinline__ float sigf(float v) { return 1.0f / (1.0f + expf(-v)); }

extern "C" __global__ void __launch_bounds__(NT, 4)
causal_loop_kernel(const int* __restrict__ settings,   // [B][T][2] int32
                   const float* __restrict__ noiseA,   // [B][T][N]
                   const float* __restrict__ noiseB,   // [B][T][N]
                   const float* __restrict__ WinA,     // [2][N]
                   const float* __restrict__ WrecA,    // [N][N]
                   const float* __restrict__ WinB,     // [2][N]
                   const float* __restrict__ WrecB,    // [N][N]
                   const float* __restrict__ Wx,       // [514][768]
                   const float* __restrict__ bg,       // [768]
                   const float* __restrict__ Wout,     // [256][2]
                   const float* __restrict__ bout,     // [2]
                   float* __restrict__ out)
{
    __shared__ float part[8][128][18];   // k-split partials (stride 18: 8B-aligned, ~conflict-free)
    __shared__ float xbuf[516][4];       // x transposed: [k][row]
    __shared__ float sAT[256][4];        // state A transposed [col][row]
    __shared__ float sBT[256][4];
    __shared__ float hzT[256][5];        // sigmoid(z) [col][row], padded
    __shared__ float hnT[256][5];        // tanh(n)
    __shared__ float ringb[4][NB][2];    // 4-deep logit ring (delay D=2)
    __shared__ float bitsf[NB][2];

    const int tid = threadIdx.x;
    const int b0  = blockIdx.x * NB;

    for (int i = tid; i < 256 * 4; i += NT) { sAT[i >> 2][i & 3] = 0.f; sBT[i >> 2][i & 3] = 0.f; }
    if (tid < 32) ((float*)ringb)[tid] = 0.f;

    // ---- GEMM-partial mapping: tid = kq*128 + g ; g = p*64 + cg
    const int kq = tid >> 7;                 // k-chunk 0..7
    const int g  = tid & 127;
    const int p  = g >> 6;                   // G: 0=z-cols,1=n-cols ; S: side A/B
    const int cg = g & 63;                   // 4-col group
    const int k0g  = kq * 64;
    const int kcnt = (kq == 7) ? 66 : 64;    // kq7 also covers k=512,513 (spins)
    const int k0s  = kq * 32;
    const float* wxp     = Wx + (size_t)k0g * 768 + (p * 512 + cg * 4);
    const float* wrp0    = (p ? WrecB : WrecA) + (size_t)k0s * 256 + cg * 4;
    const float* sTbase  = p ? &sBT[0][0] : &sAT[0][0];

    // ---- reducer mapping: thread handles triples 2*tid, 2*tid+1 (same g,r; j,j+1)
    const int gg = tid >> 3;
    const int rr = (tid >> 1) & 3;
    const int jj = (tid & 1) * 2;
    const int pp = gg >> 6;
    const int clo = (gg & 63) * 4 + jj;      // column 0..255 within half/side
    const float bgc0 = bg[pp * 512 + clo];
    const float bgc1 = bg[pp * 512 + clo + 1];
    const float* winp = pp ? WinB : WinA;
    const float wi00 = winp[clo],     wi01 = winp[256 + clo];
    const float wi10 = winp[clo + 1], wi11 = winp[256 + clo + 1];

    // ---- logits mapping (waves 0..7): wave = (r,j)
    const int lane = tid & 63;
    const int lwv  = tid >> 6;
    const int lr = (lwv >> 1) & 3, lj = lwv & 1;
    float wo0 = 0.f, wo1 = 0.f, wo2 = 0.f, wo3 = 0.f, bo = 0.f;
    if (tid < 512) {
        wo0 = Wout[lane * 2 + lj];         wo1 = Wout[(lane + 64) * 2 + lj];
        wo2 = Wout[(lane + 128) * 2 + lj]; wo3 = Wout[(lane + 192) * 2 + lj];
        bo  = bout[lj];
    }

    // ---- X-build mapping + register prefetch of next-step inputs
    const int xcc = tid & 255, xr = tid >> 8;
    const float* nApt = noiseA + (size_t)(b0 + xr) * TSTEPS * NDIM + xcc;
    const float* nBpt = noiseB + (size_t)(b0 + xr) * TSTEPS * NDIM + xcc;
    float nAreg = nApt[0], nBreg = nBpt[0];
    const int rx = tid >> 1, jx = tid & 1;
    int sreg = 0;
    if (tid < 8) sreg = settings[(size_t)(b0 + rx) * TSTEPS * 2 + jx];

    float* out0 = out;
    float* out1 = out + (size_t)BATCH * TOUT;
    float* out2 = out + (size_t)2 * BATCH * TOUT;

    __syncthreads();

    for (int t = 0; t < TSTEPS; ++t) {
        // ---------------- X: build x = [sA+nA, sB+nB, spins] (transposed), log bits
        xbuf[xcc][xr]       = sAT[xcc][xr] + nAreg;
        xbuf[256 + xcc][xr] = sBT[xcc][xr] + nBreg;
        if (t + 1 < TSTEPS) {
            nAreg = nApt[(size_t)(t + 1) * NDIM];
            nBreg = nBpt[(size_t)(t + 1) * NDIM];
        }
        if (tid < 8) {
            const float bit = (float)sreg;
            bitsf[rx][jx] = bit;
            xbuf[512 + jx][rx] = 2.f * bit - 1.f;
            if (t >= WASH) out2[((size_t)(b0 + rx) * TOUT + (t - WASH)) * 2 + jx] = bit;
            if (t + 1 < TSTEPS) sreg = settings[((size_t)(b0 + rx) * TSTEPS + (t + 1)) * 2 + jx];
        }
        __syncthreads();

        // ---------------- Gp: gx partials, 4 cols x 4 rows per thread, 1/8 of k
        {
            float a00=0,a01=0,a02=0,a03=0, a10=0,a11=0,a12=0,a13=0;
            float a20=0,a21=0,a22=0,a23=0, a30=0,a31=0,a32=0,a33=0;
            const float* xp = &xbuf[k0g][0];
            #pragma unroll 4
            for (int kk = 0; kk < kcnt; ++kk) {
                const float4 w  = *(const float4*)(wxp + (size_t)kk * 768);
                const float4 xv = *(const float4*)(xp + kk * 4);
                a00 = fmaf(xv.x, w.x, a00); a01 = fmaf(xv.x, w.y, a01); a02 = fmaf(xv.x, w.z, a02); a03 = fmaf(xv.x, w.w, a03);
                a10 = fmaf(xv.y, w.x, a10); a11 = fmaf(xv.y, w.y, a11); a12 = fmaf(xv.y, w.z, a12); a13 = fmaf(xv.y, w.w, a13);
                a20 = fmaf(xv.z, w.x, a20); a21 = fmaf(xv.z, w.y, a21); a22 = fmaf(xv.z, w.z, a22); a23 = fmaf(xv.z, w.w, a23);
                a30 = fmaf(xv.w, w.x, a30); a31 = fmaf(xv.w, w.y, a31); a32 = fmaf(xv.w, w.z, a32); a33 = fmaf(xv.w, w.w, a33);
            }
            float* pb = &part[kq][g][0];
            *(float2*)(pb +  0) = make_float2(a00, a01); *(float2*)(pb +  2) = make_float2(a02, a03);
            *(float2*)(pb +  4) = make_float2(a10, a11); *(float2*)(pb +  6) = make_float2(a12, a13);
            *(float2*)(pb +  8) = make_float2(a20, a21); *(float2*)(pb + 10) = make_float2(a22, a23);
            *(float2*)(pb + 12) = make_float2(a30, a31); *(float2*)(pb + 14) = make_float2(a32, a33);
        }
        __syncthreads();

        // ---------------- Gr: reduce 8 partials, bias, activation -> hzT / hnT
        {
            float e0 = bgc0, e1 = bgc1;
            #pragma unroll
            for (int q = 0; q < 8; ++q) {
                const float2 pr = *(const float2*)&part[q][gg][rr * 4 + jj];
                e0 += pr.x; e1 += pr.y;
            }
            if (pp == 0) { hzT[clo][rr] = sigf(e0);  hzT[clo + 1][rr] = sigf(e1); }
            else         { hnT[clo][rr] = tanhf(e0); hnT[clo + 1][rr] = tanhf(e1); }
        }
        __syncthreads();

        // ---------------- Sp: reservoir partials (side p), plus L (logits) on waves 0..7
        {
            float a00=0,a01=0,a02=0,a03=0, a10=0,a11=0,a12=0,a13=0;
            float a20=0,a21=0,a22=0,a23=0, a30=0,a31=0,a32=0,a33=0;
            const float* sp = sTbase + k0s * 4;
            #pragma unroll 4
            for (int kk = 0; kk < 32; ++kk) {
                const float4 w  = *(const float4*)(wrp0 + (size_t)kk * 256);
                const float4 sv = *(const float4*)(sp + kk * 4);
                a00 = fmaf(sv.x, w.x, a00); a01 = fmaf(sv.x, w.y, a01); a02 = fmaf(sv.x, w.z, a02); a03 = fmaf(sv.x, w.w, a03);
                a10 = fmaf(sv.y, w.x, a10); a11 = fmaf(sv.y, w.y, a11); a12 = fmaf(sv.y, w.z, a12); a13 = fmaf(sv.y, w.w, a13);
                a20 = fmaf(sv.z, w.x, a20); a21 = fmaf(sv.z, w.y, a21); a22 = fmaf(sv.z, w.z, a22); a23 = fmaf(sv.z, w.w, a23);
                a30 = fmaf(sv.w, w.x, a30); a31 = fmaf(sv.w, w.y, a31); a32 = fmaf(sv.w, w.z, a32); a33 = fmaf(sv.w, w.w, a33);
            }
            float* pb = &part[kq][g][0];
            *(float2*)(pb +  0) = make_float2(a00, a01); *(float2*)(pb +  2) = make_float2(a02, a03);
            *(float2*)(pb +  4) = make_float2(a10, a11); *(float2*)(pb +  6) = make_float2(a12, a13);
            *(float2*)(pb +  8) = make_float2(a20, a21); *(float2*)(pb + 10) = make_float2(a22, a23);
            *(float2*)(pb + 12) = make_float2(a30, a31); *(float2*)(pb + 14) = make_float2(a32, a33);
        }
        if (tid < 512) {  // logits: h = (1-z)*n ; one wave per (r,j)
            const float h0v = (1.f - hzT[lane      ][lr]) * hnT[lane      ][lr];
            const float h1v = (1.f - hzT[lane +  64][lr]) * hnT[lane +  64][lr];
            const float h2v = (1.f - hzT[lane + 128][lr]) * hnT[lane + 128][lr];
            const float h3v = (1.f - hzT[lane + 192][lr]) * hnT[lane + 192][lr];
            float pl = fmaf(h0v, wo0, fmaf(h1v, wo1, fmaf(h2v, wo2, h3v * wo3)));
            #pragma unroll
            for (int s = 32; s; s >>= 1) pl += __shfl_down(pl, s, 64);
            if (lane == 0) {
                const float lg = pl + bo;
                ringb[t & 3][lr][lj] = lg;
                if (t >= WASH) {
                    const float sg = (lg > 0.f) ? 1.f : ((lg < 0.f) ? -1.f : 0.f);
                    (lj ? out1 : out0)[(size_t)(b0 + lr) * TOUT + (t - WASH)] = sg;
                }
            }
        }
        __syncthreads();

        // ---------------- Sr: reduce, add input terms (bit, delayed logit), tanh -> new state
        {
            float e0 = 0.f, e1 = 0.f;
            #pragma unroll
            for (int q = 0; q < 8; ++q) {
                const float2 pr = *(const float2*)&part[q][gg][rr * 4 + jj];
                e0 += pr.x; e1 += pr.y;
            }
            const float bit = bitsf[rr][pp];
            const float dly = ringb[(t + 2) & 3][rr][pp];   // logits from t-2
            const float v0 = tanhf(e0 + bit * wi00 + dly * wi01);
            const float v1 = tanhf(e1 + bit * wi10 + dly * wi11);
            float* st = pp ? &sBT[0][0] : &sAT[0][0];
            st[clo * 4 + rr]       = v0;
            st[(clo + 1) * 4 + rr] = v1;
        }
        __syncthreads();
    }
}

extern "C" void kernel_launch(void* const* d_in, const int* in_sizes, int n_in,
                              void* d_out, int out_size, void* d_ws, size_t ws_size,
                              hipStream_t stream) {
    (void)in_sizes; (void)n_in; (void)d_ws; (void)ws_size; (void)out_size;
    causal_loop_kernel<<<NBLK, NT, 0, stream>>>(
        (const int*)d_in[0],     // settings_seq
        (const float*)d_in[1],   // noise_seq_A
        (const float*)d_in[2],   // noise_seq_B
        (const float*)d_in[3],   // W_in_A
        (const float*)d_in[4],   // W_rec_A
        (const float*)d_in[5],   // W_in_B
        (const float*)d_in[6],   // W_rec_B
        (const float*)d_in[7],   // Wx  (d_in[8]=Wh unused since h0==0)
        (const float*)d_in[9],   // b_gru
        (const float*)d_in[10],  // Wout
        (const float*)d_in[11],  // b_out
        (float*)d_out);
}

// Round 3
// 6279.019 us; speedup vs baseline: 3.1749x; 1.1411x over previous
//
#include <hip/hip_runtime.h>
#include <cmath>

#define BATCH 256
#define TSTEPS 512
#define NDIM 256
#define WASH 64
#define TOUT (TSTEPS - WASH)   /* 448 */
#define NB 8                   /* batch rows per team */
#define CS 8                   /* column-split blocks per team */
#define NTEAM (BATCH / NB)     /* 32 */
#define NBLK (NTEAM * CS)      /* 256 */
#define NT 1024

/* workspace layout (floats) */
#define SBUF_SZ (3 * BATCH * 512)            /* state triple buffer [3][256][512] */
#define RING_OFF SBUF_SZ
#define RING_SZ (4 * NTEAM * CS * 16)        /* logit partials [4][32][8][r8*2(+pad)] */
#define CTR_OFF (RING_OFF + RING_SZ)
#define CTR_SZ (NTEAM * 16)

__global__ void init_kernel(float* ws) {
    const int n0 = BATCH * 512;              /* sbuf[0] must start zero */
    const int n1 = RING_SZ + CTR_SZ;
    for (int i = blockIdx.x * blockDim.x + threadIdx.x; i < n0 + n1;
         i += gridDim.x * blockDim.x) {
        float* p = (i < n0) ? (ws + i) : (ws + RING_OFF + (i - n0));
        __hip_atomic_store(p, 0.f, __ATOMIC_RELAXED, __HIP_MEMORY_SCOPE_AGENT);
    }
}

__global__ void __launch_bounds__(NT, 4)
loop_kernel(const int* __restrict__ settings, const float* __restrict__ noiseA,
            const float* __restrict__ noiseB, const float* __restrict__ WinA,
            const float* __restrict__ WrecA, const float* __restrict__ WinB,
            const float* __restrict__ WrecB, const float* __restrict__ Wx,
            const float* __restrict__ bg, const float* __restrict__ Wout,
            const float* __restrict__ bout, float* __restrict__ out, float* ws)
{
    __shared__ float xbuf[516][8];   /* x transposed [k][row] (s+noise, spins) */
    __shared__ float sT[512][8];     /* raw state transposed [k][row]          */
    __shared__ float part[16][64][9];/* k-split partials, padded row           */
    __shared__ float hzT[32][9];     /* sigmoid(z) [hc][row], padded           */
    __shared__ float hnT[32][9];     /* tanh(n)                                */
    __shared__ float bitsf[8][2];
    __shared__ float dly[8][2];      /* reduced delayed logits (t-2)           */

    const int tid  = threadIdx.x;
    const int cs   = blockIdx.x >> 5;   /* team blocks land on same XCD under %8 rr */
    const int team = blockIdx.x & 31;
    const int r0   = team * NB;

    float* ring   = ws + RING_OFF;
    unsigned* ctr = (unsigned*)(ws + CTR_OFF) + team * 16;

    /* GEMM mapping: tid = kq*64 + rh*32 + c2 */
    const int kq = tid >> 6;
    const int rh = (tid >> 5) & 1;
    const int c2 = tid & 31;
    const float* wxp0 = Wx + ((c2 < 16) ? (cs * 32 + 2 * c2)
                                        : (512 + cs * 32 + 2 * (c2 - 16)));
    const int side  = cs >> 2;               /* 0 = A, 1 = B */
    const int scol0 = (cs & 3) * 64;
    const float* wrp0 = (side ? WrecB : WrecA) + (scol0 + 2 * c2);
    const float* wins = side ? WinB : WinA;

    /* X mapping */
    const int xk = tid & 511;
    const int xh = tid >> 9;                 /* row-half */

    /* Gr / Sr preloaded constants */
    float biasg = 0.f, win0r = 0.f, win1r = 0.f;
    if (tid < 512) {
        const int oc = tid & 63;
        biasg = bg[(oc < 32) ? (cs * 32 + oc) : (512 + cs * 32 + (oc - 32))];
        win0r = wins[scol0 + oc];
        win1r = wins[NDIM + scol0 + oc];
    }
    /* logits mapping: wave wv = (r, j), lanes < 32 hold h-cols */
    const int lane = tid & 63;
    const int wv = tid >> 6;
    const int lr = wv >> 1, lj = wv & 1;
    const float woreg = (lane < 32) ? Wout[(cs * 32 + lane) * 2 + lj] : 0.f;

    float* out0 = out;
    float* out1 = out + (size_t)BATCH * TOUT;
    float* out2 = out + (size_t)2 * BATCH * TOUT;

    for (int t = 0; t < TSTEPS; ++t) {
        const int sb_r = t % 3, sb_w = (t + 1) % 3;

        /* ---- X: gather state (coherent) + noise -> xbuf / sT; bits; delayed reduce */
        {
            float* srow = ws + sb_r * (BATCH * 512);
            float v[4], u[4];
            #pragma unroll
            for (int q = 0; q < 4; ++q) {
                const int r = xh * 4 + q;
                const float sv = __hip_atomic_load(&srow[(size_t)(r0 + r) * 512 + xk],
                                                   __ATOMIC_RELAXED, __HIP_MEMORY_SCOPE_AGENT);
                u[q] = sv;
                const float nv = (xk < 256)
                    ? noiseA[((size_t)(r0 + r) * TSTEPS + t) * NDIM + xk]
                    : noiseB[((size_t)(r0 + r) * TSTEPS + t) * NDIM + (xk - 256)];
                v[q] = sv + nv;
            }
            *(float4*)&xbuf[xk][xh * 4] = make_float4(v[0], v[1], v[2], v[3]);
            *(float4*)&sT[xk][xh * 4]   = make_float4(u[0], u[1], u[2], u[3]);
        }
        if (tid < 16) {                       /* bits + spins (+ out2 by cs0) */
            const int r = tid >> 1, j = tid & 1;
            const float bit = (float)settings[((size_t)(r0 + r) * TSTEPS + t) * 2 + j];
            bitsf[r][j] = bit;
            xbuf[512 + j][r] = 2.f * bit - 1.f;
            if (cs == 0 && t >= WASH)
                out2[((size_t)(r0 + r) * TOUT + (t - WASH)) * 2 + j] = bit;
        } else if (tid < 32) {                /* reduce delayed logits (t-2) */
            const int r = (tid - 16) >> 1, j = tid & 1;
            float s = bout[j];
            #pragma unroll
            for (int q = 0; q < CS; ++q)
                s += __hip_atomic_load(
                    &ring[((((size_t)((t + 2) & 3)) * NTEAM + team) * CS + q) * 16 + r * 2 + j],
                    __ATOMIC_RELAXED, __HIP_MEMORY_SCOPE_AGENT);
            dly[r][j] = s;
            if (cs == 0 && t - 2 >= WASH) {   /* sign outputs for step t-2 */
                const float sg = (s > 0.f) ? 1.f : ((s < 0.f) ? -1.f : 0.f);
                (j ? out1 : out0)[(size_t)(r0 + r) * TOUT + (t - 2 - WASH)] = sg;
            }
        }
        __syncthreads();

        /* ---- Gp: gx partials (2 cols x 4 rows, 1/16 of k) ---- */
        {
            const int kbeg = kq * 32;
            const int kend = (kq == 15) ? 514 : kbeg + 32;
            float a00 = 0, a01 = 0, a10 = 0, a11 = 0, a20 = 0, a21 = 0, a30 = 0, a31 = 0;
            const float* wp = wxp0 + (size_t)kbeg * 768;
            #pragma unroll 4
            for (int k = kbeg; k < kend; ++k, wp += 768) {
                const float2 w  = *(const float2*)wp;
                const float4 xv = *(const float4*)&xbuf[k][rh * 4];
                a00 = fmaf(xv.x, w.x, a00); a01 = fmaf(xv.x, w.y, a01);
                a10 = fmaf(xv.y, w.x, a10); a11 = fmaf(xv.y, w.y, a11);
                a20 = fmaf(xv.z, w.x, a20); a21 = fmaf(xv.z, w.y, a21);
                a30 = fmaf(xv.w, w.x, a30); a31 = fmaf(xv.w, w.y, a31);
            }
            float* pb = &part[kq][rh * 32 + c2][0];
            pb[0] = a00; pb[1] = a10; pb[2] = a20; pb[3] = a30;
            pb[4] = a01; pb[5] = a11; pb[6] = a21; pb[7] = a31;
        }
        __syncthreads();

        /* ---- Gr: reduce 16 partials + bias + activation ---- */
        if (tid < 512) {
            const int rr = tid >> 6, oc = tid & 63;
            const int g = (rr >> 2) * 32 + (oc >> 1);
            const int i = (oc & 1) * 4 + (rr & 3);
            float e = biasg;
            #pragma unroll
            for (int q = 0; q < 16; ++q) e += part[q][g][i];
            if (oc < 32) hzT[oc][rr] = 1.f / (1.f + expf(-e));
            else         hnT[oc - 32][rr] = tanhf(e);
        }
        __syncthreads();

        /* ---- logits partial (all waves) + Sp: reservoir partials ---- */
        {
            float pl = 0.f;
            if (lane < 32)
                pl = (1.f - hzT[lane][lr]) * hnT[lane][lr] * woreg;
            #pragma unroll
            for (int s = 16; s; s >>= 1) pl += __shfl_down(pl, s, 64);
            if (lane == 0)
                __hip_atomic_store(
                    &ring[((((size_t)(t & 3)) * NTEAM + team) * CS + cs) * 16 + lr * 2 + lj],
                    pl, __ATOMIC_RELAXED, __HIP_MEMORY_SCOPE_AGENT);
        }
        {
            const int kbeg = kq * 16;
            float a00 = 0, a01 = 0, a10 = 0, a11 = 0, a20 = 0, a21 = 0, a30 = 0, a31 = 0;
            const float* wp = wrp0 + (size_t)kbeg * 256;
            #pragma unroll 4
            for (int k = kbeg; k < kbeg + 16; ++k, wp += 256) {
                const float2 w  = *(const float2*)wp;
                const float4 sv = *(const float4*)&sT[side * 256 + k][rh * 4];
                a00 = fmaf(sv.x, w.x, a00); a01 = fmaf(sv.x, w.y, a01);
                a10 = fmaf(sv.y, w.x, a10); a11 = fmaf(sv.y, w.y, a11);
                a20 = fmaf(sv.z, w.x, a20); a21 = fmaf(sv.z, w.y, a21);
                a30 = fmaf(sv.w, w.x, a30); a31 = fmaf(sv.w, w.y, a31);
            }
            __syncthreads();   /* Gr partial reads done before overwrite */
            float* pb = &part[kq][rh * 32 + c2][0];
            pb[0] = a00; pb[1] = a10; pb[2] = a20; pb[3] = a30;
            pb[4] = a01; pb[5] = a11; pb[6] = a21; pb[7] = a31;
        }
        __syncthreads();

        /* ---- Sr: reduce + input terms + tanh -> coherent state write ---- */
        if (tid < 512) {
            const int rr = tid >> 6, sc = tid & 63;
            const int g = (rr >> 2) * 32 + (sc >> 1);
            const int i = (sc & 1) * 4 + (rr & 3);
            float e = 0.f;
            #pragma unroll
            for (int q = 0; q < 16; ++q) e += part[q][g][i];
            e += bitsf[rr][side] * win0r + dly[rr][side] * win1r;
            const float v = tanhf(e);
            __hip_atomic_store(
                &ws[(size_t)sb_w * (BATCH * 512) + (size_t)(r0 + rr) * 512 + side * 256 + scol0 + sc],
                v, __ATOMIC_RELAXED, __HIP_MEMORY_SCOPE_AGENT);
        }
        __syncthreads();

        /* ---- team barrier (monotonic counter, one per step) ---- */
        if (tid == 0) {
            __hip_atomic_fetch_add(ctr, 1u, __ATOMIC_RELEASE, __HIP_MEMORY_SCOPE_AGENT);
            const unsigned tgt = (unsigned)(CS * (t + 1));
            long guard = 0;
            while (__hip_atomic_load(ctr, __ATOMIC_RELAXED, __HIP_MEMORY_SCOPE_AGENT) < tgt) {
                __builtin_amdgcn_s_sleep(2);
                if (++guard > 100000000L) break;   /* hang insurance */
            }
            __hip_atomic_load(ctr, __ATOMIC_ACQUIRE, __HIP_MEMORY_SCOPE_AGENT);
        }
        __syncthreads();
    }

    /* ---- tail: sign outputs for t-2 = 510, 511 (cs0) ---- */
    if (cs == 0 && tid >= 16 && tid < 32) {
        const int r = (tid - 16) >> 1, j = tid & 1;
        #pragma unroll
        for (int tt = TSTEPS; tt < TSTEPS + 2; ++tt) {
            float s = bout[j];
            #pragma unroll
            for (int q = 0; q < CS; ++q)
                s += __hip_atomic_load(
                    &ring[((((size_t)((tt + 2) & 3)) * NTEAM + team) * CS + q) * 16 + r * 2 + j],
                    __ATOMIC_RELAXED, __HIP_MEMORY_SCOPE_AGENT);
            const float sg = (s > 0.f) ? 1.f : ((s < 0.f) ? -1.f : 0.f);
            (j ? out1 : out0)[(size_t)(r0 + r) * TOUT + (tt - 2 - WASH)] = sg;
        }
    }
}

extern "C" void kernel_launch(void* const* d_in, const int* in_sizes, int n_in,
                              void* d_out, int out_size, void* d_ws, size_t ws_size,
                              hipStream_t stream) {
    (void)in_sizes; (void)n_in; (void)ws_size; (void)out_size;
    float* ws = (float*)d_ws;
    hipLaunchKernelGGL(init_kernel, dim3(128), dim3(256), 0, stream, ws);

    const int*   settings = (const int*)d_in[0];
    const float* noiseA   = (const float*)d_in[1];
    const float* noiseB   = (const float*)d_in[2];
    const float* WinA     = (const float*)d_in[3];
    const float* WrecA    = (const float*)d_in[4];
    const float* WinB     = (const float*)d_in[5];
    const float* WrecB    = (const float*)d_in[6];
    const float* Wx       = (const float*)d_in[7];   /* d_in[8] = Wh unused (h0 == 0) */
    const float* bg       = (const float*)d_in[9];
    const float* Wout     = (const float*)d_in[10];
    const float* bout     = (const float*)d_in[11];
    float*       outp     = (float*)d_out;

    void* args[] = { &settings, &noiseA, &noiseB, &WinA, &WrecA, &WinB, &WrecB,
                     &Wx, &bg, &Wout, &bout, &outp, &ws };
    hipLaunchCooperativeKernel((void*)loop_kernel, dim3(NBLK), dim3(NT),
                               args, 0, stream);
}